// Round 1
// baseline (101.071 us; speedup 1.0000x reference)
//
#include <hip/hip_runtime.h>

// SimplePitchEstimator on MI355X (gfx950).
// ac = irfft(rfft(x,512)^2) == linear self-convolution c[n] = sum y[i]y[n-i],
// y = x - mean(x). Round-13: load/compute phase stagger via s_sleep.
//
// Evidence chain (r12 counters): timed graph = 2x 42.5us harness poison
// fills (256MiB each, immutable) + ~12.1us pitch_kernel (absent from
// top-5 => <41us; 97.17 - 85.04 = 12.13). Kernel floor: 41.9MB reads =
// 6.7us HBM; conv = ~6.1us per-SIMD VALU issue. 12.1 ~= 6.7 + 6.1 =>
// phases run back-to-back, ~zero overlap: all blocks issue loads at t=0,
// fair HBM sharing completes everyone at ~6.7us, then one chip-wide VALU
// burst. Fix: stagger block groups (blk>>8)&3 by ~1.3us each
// (s_sleep(48)); under round-robin dispatch the 4 co-resident blocks per
// CU are {c,c+256,c+512,c+768} = one per group, so each CU pipelines
// load(g+1) under conv(g). Predicted kernel ~9-10us, dur_us ~94-95.
// Neutral (not regressing) if dispatch mapping is chunked instead.
// Also: center v[] in place, pm via fmaxf(c,-c) (v_max3 w/ neg mod),
// phase D reuses centered values (-~80 VALU instr/thread, bit-identical).
//
//  * Six NAMED float4 vars W0..W5 hold the 6 window quads; quad->var map
//    (quad % 6) repeats every 6 rounds -> clean loop unrolled x6; every
//    reference is a static component of a named var (no array).
//  * Refill ds_read_b128 directly into the rotating target var, placed
//    after the round's FMAs (latency covered by next round); x quads via
//    2-var ping-pong (trip length 6 even -> static parity).
//  * Remainder + ragged rounds statically unrolled, affine masks
//    8r+2d < N0+j.
//  * Half-sum c[n] = 2*sum_{2i<n} y_i y_{n-i} + center (validated r6-r10).
//  * LDS 160x64x4 = 40960 B exactly (4 blocks/CU, 1024 blocks co-resident);
//    balanced tile pairs 27/27/28/28; mu folded at LDS write; silent-check
//    pm rides in a register to the final reduction (no phase C).

#define SR_F    16000.0f
#define HOPSZ   256
#define TFRAMES 4096
#define SAMPLES 1048576

#define CMP(v_, c_) ((c_) == 0 ? (v_).x : (c_) == 1 ? (v_).y : \
                     (c_) == 2 ? (v_).z : (v_).w)

template<int N0>
__device__ __forceinline__ void conv_tile(const float4* __restrict__ col4,
                                          const float* __restrict__ colf,
                                          float& best, int& bl) {
    constexpr int J    = 15;
    constexpr int B0   = ((N0 - 3) / 4) * 4;   // aligned window base row
    constexpr int Q0   = B0 / 4;               // base quad at round 0
    constexpr int KOFF = N0 - B0;              // 3..6
    constexpr int IC   = (N0 + J) / 2;         // i-count for max lag
    constexpr int RT   = (IC + 3) / 4;         // total rounds
    constexpr int RC   = (N0 - 6 + 7) / 8;     // clean rounds (8r+6 < N0)
    constexpr int T    = RC / 6;               // runtime x6 trips
    constexpr int R6   = 6 * T;                // first static round
    static_assert(KOFF >= 3 && KOFF + J - 1 <= 20, "window index bound");
    static_assert(RC >= 1 && RC <= RT - 1, "clean/ragged split");
    static_assert(Q0 - RT + 1 >= 0, "refill quad in range");

    float acc[J];
    #pragma unroll
    for (int j = 0; j < J; ++j) acc[j] = 0.f;

    float4 W0_, W1_, W2_, W3_, W4_, W5_, xa_, xb_;

#define WREAD(vi_, c_) \
    ((vi_) == 0 ? CMP(W0_, c_) : (vi_) == 1 ? CMP(W1_, c_) : \
     (vi_) == 2 ? CMP(W2_, c_) : (vi_) == 3 ? CMP(W3_, c_) : \
     (vi_) == 4 ? CMP(W4_, c_) : CMP(W5_, c_))

#define WSTORE(vi_, e_) do {                                              \
    if      ((vi_) == 0) W0_ = (e_); else if ((vi_) == 1) W1_ = (e_);     \
    else if ((vi_) == 2) W2_ = (e_); else if ((vi_) == 3) W3_ = (e_);     \
    else if ((vi_) == 4) W4_ = (e_); else                 W5_ = (e_);     \
    } while (0)

    // round with round-index R_ (mask/parity) and rotation phase K_ (=R_ mod 6
    // folded statically); MASKED_=1 enables the ragged-term prune.
#define ROUND_BODY(K_, R_, MASKED_)                                       \
    {                                                                     \
        const float4 xc = ((R_) & 1) ? xb_ : xa_;                         \
        _Pragma("unroll")                                                 \
        for (int d = 0; d < 4; ++d) {                                     \
            const float xv = CMP(xc, d);                                  \
            _Pragma("unroll")                                             \
            for (int j = 0; j < J; ++j) {                                 \
                if (!(MASKED_) || (8 * (R_) + 2 * d < N0 + j)) {          \
                    const int g  = KOFF + j - d;                          \
                    const int vi = ((Q0 + g / 4 - (K_)) % 6 + 6) % 6;     \
                    acc[j] = fmaf(xv, WREAD(vi, g & 3), acc[j]);          \
                }                                                         \
            }                                                             \
        }                                                                 \
    }

    // ---- init: quads Q0..Q0+5 into vars (Q0+i)%6 (clip quads>39), x quad 0
    #pragma unroll
    for (int i = 0; i < 6; ++i) {
        const float4 q = (Q0 + i <= 39) ? col4[(Q0 + i) * 64]
                                        : make_float4(0.f, 0.f, 0.f, 0.f);
        WSTORE((Q0 + i) % 6, q);
    }
    xa_ = col4[0];

    // ---- runtime x6 trips: rounds r = 6t+k, all clean ----
    const float4* xq = col4;                 // x base: quad 6t
    const float4* wq = col4 + Q0 * 64;       // refill base: quad Q0-6t
    #pragma unroll 1
    for (int t = 0; t < T; ++t) {
        #pragma unroll
        for (int k = 0; k < 6; ++k) {
            if (((k + 1) & 1) == 0) xa_ = xq[(k + 1) * 64];
            else                    xb_ = xq[(k + 1) * 64];
            ROUND_BODY(k, k, 0)
            // refill quad Q0-6t-k-1 -> var just freed this round
            WSTORE(((Q0 - k - 1) % 6 + 6) % 6, wq[-(k + 1) * 64]);
        }
        xq += 6 * 64;
        wq -= 6 * 64;
    }

    // ---- static rounds rr = R6..RT-1 (clean remainder + ragged) ----
    #pragma unroll
    for (int u = 0; u < RT - R6; ++u) {
        const int rr = R6 + u;                       // constant after unroll
        if (rr + 1 < RT) {                           // compile-time guard
            if (((rr + 1) & 1) == 0) xa_ = col4[(rr + 1) * 64];
            else                     xb_ = col4[(rr + 1) * 64];
        }
        ROUND_BODY(rr, rr, (rr >= RC))
        if (rr + 1 < RT)
            WSTORE(((Q0 - rr - 1) % 6 + 6) % 6, col4[(Q0 - rr - 1) * 64]);
    }

    // ---- finalize: x2 + center term for even lags, local argmax ----
    #pragma unroll
    for (int j = 0; j < J; ++j) {
        float v2 = acc[j] + acc[j];
        if ((N0 + j) % 2 == 0) {
            const int R = (N0 + j) / 2;              // constant after unroll
            const float c = colf[(R / 4) * 256 + (R & 3)];
            v2 = fmaf(c, c, v2);
        }
        if (v2 > best) { best = v2; bl = N0 + j; }   // strict >: first max
    }
#undef ROUND_BODY
#undef WSTORE
#undef WREAD
}

__global__ __launch_bounds__(256)
void pitch_kernel(const float* __restrict__ audio, float* __restrict__ out) {
    __shared__ float4 X4[40 * 64];                   // 40960 B exactly
    float* Xa = reinterpret_cast<float*>(X4);

    const int tid = threadIdx.x;
    const int s   = tid >> 6;          // wave id
    const int f   = tid & 63;          // frame within block
    const int blk = blockIdx.x;
    const int b   = blk >> 6;          // batch row
    const int t0  = (blk & 63) << 6;   // first frame of block

    // ---- Phase stagger: group g = (blk>>8)&3 sleeps ~g*1.3us so HBM
    // serves one block-group per CU at a time; conv(g) overlaps load(g+1).
    // Under round-robin dispatch, CU c hosts {c, c+256, c+512, c+768} =
    // one block per group. Undersleep on purpose (graceful degradation).
    {
        const int grp = (blk >> 8) & 3;
        for (int i = 0; i < grp; ++i) __builtin_amdgcn_s_sleep(48);
        __builtin_amdgcn_sched_barrier(0);           // keep loads below
    }

    // ---- Phase A: load 40 samples of frame f (chunk s), partial sum ----
    const float* g = audio + (size_t)b * SAMPLES + (size_t)(t0 + f) * HOPSZ + s * 40;
    float v[40];
    float ps = 0.f;
    #pragma unroll
    for (int j = 0; j < 10; ++j) {
        float4 q = reinterpret_cast<const float4*>(g)[j];   // 16B-aligned
        v[4*j+0] = q.x; v[4*j+1] = q.y; v[4*j+2] = q.z; v[4*j+3] = q.w;
        ps += q.x + q.y + q.z + q.w;
    }

    // ---- Phase B: block mean via aux rows; pm stays in a register ----
    Xa[s * 64 + f] = ps;
    __syncthreads();
    const float mu = (Xa[f] + Xa[64 + f] + Xa[128 + f] + Xa[192 + f]) * (1.0f / 160.0f);
    // center in place; pm = max|c| via fmax(c,-c) (v_max3 w/ neg modifier)
    #pragma unroll
    for (int q = 0; q < 40; ++q) v[q] = v[q] - mu;
    float pm = 0.f;
    #pragma unroll
    for (int q = 0; q < 40; ++q) pm = fmaxf(pm, fmaxf(v[q], -v[q]));
    __syncthreads();                       // sum-reads done before D overwrites

    // ---- Phase D: write centered frames as row-quads (b128, contiguous) ----
    #pragma unroll
    for (int k = 0; k < 10; ++k)
        X4[(10 * s + k) * 64 + f] =
            make_float4(v[4*k+0], v[4*k+1], v[4*k+2], v[4*k+3]);
    __syncthreads();

    // ---- Phase E: paired balanced tiles (rounds 27/27/28/28) ----
    const float4* col4 = X4 + f;
    const float*  colf = Xa + 4 * f;
    float best = -3.4e38f; int bl = 0;
    if      (s == 0) { conv_tile< 40>(col4, colf, best, bl);
                       conv_tile<145>(col4, colf, best, bl); }
    else if (s == 1) { conv_tile< 55>(col4, colf, best, bl);
                       conv_tile<130>(col4, colf, best, bl); }
    else if (s == 2) { conv_tile< 70>(col4, colf, best, bl);
                       conv_tile<115>(col4, colf, best, bl); }
    else             { conv_tile< 85>(col4, colf, best, bl);
                       conv_tile<100>(col4, colf, best, bl); }
    __syncthreads();                       // conv done: X now dead

    // ---- Phase F: cross-wave argmax + silent-check via aux rows ----
    Xa[s * 64 + f] = best;
    reinterpret_cast<int*>(Xa)[256 + s * 64 + f] = bl;
    Xa[512 + s * 64 + f] = pm;
    __syncthreads();

    if (s == 0) {
        float bv = Xa[f];
        int   L  = reinterpret_cast<int*>(Xa)[256 + f];
        #pragma unroll
        for (int c = 1; c < 4; ++c) {
            const float vv = Xa[c * 64 + f];
            const int   lv = reinterpret_cast<int*>(Xa)[256 + c * 64 + f];
            if (vv > bv || (vv == bv && lv < L)) { bv = vv; L = lv; }
        }
        const float mx = fmaxf(fmaxf(Xa[512 + f], Xa[512 + 64 + f]),
                               fmaxf(Xa[512 + 128 + f], Xa[512 + 192 + f]));
        const float pitch = SR_F / (float)L;
        out[(size_t)b * TFRAMES + t0 + f] = (mx < 1e-8f) ? 0.0f : pitch;
    }
}

extern "C" void kernel_launch(void* const* d_in, const int* in_sizes, int n_in,
                              void* d_out, int out_size, void* d_ws, size_t ws_size,
                              hipStream_t stream) {
    const float* audio = (const float*)d_in[0];
    float* out = (float*)d_out;
    pitch_kernel<<<dim3(1024), dim3(256), 0, stream>>>(audio, out);
}